// Round 9
// baseline (435.192 us; speedup 1.0000x reference)
//
#include <hip/hip_runtime.h>

typedef __attribute__((ext_vector_type(8))) short short8;
typedef __attribute__((ext_vector_type(4))) float f32x4;
typedef __attribute__((ext_vector_type(4))) unsigned short u16x4;
typedef __attribute__((ext_vector_type(8))) unsigned short u16x8;

#define H 112
#define W 112
#define HP 114
#define WP 114
#define CIN 128
#define COUT 256
#define NPIX (H * W)          // 12544
#define NIMG 32
#define MTOT (NIMG * NPIX)    // 401408
#define PADELEMS ((long)NIMG * HP * WP * CIN)  // 53,231,616
#define NPADPIX (NIMG * HP * WP)               // 415,872 padded pixels

__device__ __forceinline__ unsigned short f2bf(float f) {
    unsigned int u = __builtin_bit_cast(unsigned int, f);
    u += 0x7FFFu + ((u >> 16) & 1u);
    return (unsigned short)(u >> 16);
}

__device__ __forceinline__ void gl2lds16(const void* g, void* l) {
    __builtin_amdgcn_global_load_lds(
        (const __attribute__((address_space(1))) unsigned int*)g,
        (__attribute__((address_space(3))) unsigned int*)l,
        16, 0, 0);
}

// output pixel p -> padded-image linear pixel index
__device__ __forceinline__ int pidx(int p) {
    int n = p / NPIX;
    int r = p - n * NPIX;
    int oh = r / W, ow = r - oh * W;
    return n * (HP * WP) + (oh + 1) * WP + ow + 1;
}

// ---- weights bf16 {+1,-1}, layout [tap][kc4][kq4][cout256][e8] ----
__global__ void binw3_kernel(const float* __restrict__ kw, unsigned short* __restrict__ bw) {
    int tid = blockIdx.x * 256 + threadIdx.x;
    int e    = tid & 7;
    int cout = (tid >> 3) & 255;
    int q    = (tid >> 11) & 3;
    int kc   = (tid >> 13) & 3;
    int tap  = tid >> 15;
    int cin  = kc * 32 + q * 8 + e;
    float w = kw[(tap * 128 + cin) * 256 + cout];
    bw[tid] = (w >= 0.0f) ? (unsigned short)0x3F80u : (unsigned short)0xBF80u;
}

// ---- x (f32 NHWC) -> zero-padded bf16 [N][114][114][128] ----
__global__ void pad_kernel(const float* __restrict__ x, unsigned short* __restrict__ xp) {
    long tid = (long)blockIdx.x * 256 + threadIdx.x;   // one thread = 8 elems
    if (tid >= PADELEMS / 8) return;
    int c8 = (int)(tid & 15);
    long rem = tid >> 4;
    int wp = (int)(rem % WP); rem /= WP;
    int hp = (int)(rem % HP);
    int n  = (int)(rem / HP);
    u16x8 v = {0, 0, 0, 0, 0, 0, 0, 0};
    if (hp >= 1 && hp <= H && wp >= 1 && wp <= W) {
        const float* s = x + (((long)(n * H + hp - 1) * W + (wp - 1)) * CIN + c8 * 8);
        f32x4 a = *(const f32x4*)s;
        f32x4 b = *(const f32x4*)(s + 4);
        v = (u16x8){ f2bf(a.x), f2bf(a.y), f2bf(a.z), f2bf(a.w),
                     f2bf(b.x), f2bf(b.y), f2bf(b.z), f2bf(b.w) };
    }
    *(u16x8*)(xp + tid * 8) = v;
}

// ---- conv9: A-halo LDS (staged once per cin-chunk) + B direct-to-register ----
// Tile 512(M) x 128(N), 8 waves (4M x 2N), per-wave 128x64, 16x16x32 MFMA.
// Inner 9-tap loop is barrier-free; taps read the halo at compile-time offsets.
__global__ __launch_bounds__(512, 2)
void conv9_kernel(const unsigned short* __restrict__ xp, const unsigned short* __restrict__ bw,
                  float* __restrict__ out) {
    __shared__ unsigned short Ah[4 * 1024 * 8];   // 64 KB: [kq][slot1024][8 shorts]

    const int tid = threadIdx.x;
    const int swz = (blockIdx.x & 7) * 196 + (blockIdx.x >> 3);  // 1568 = 8*196, bijective
    const int bm = swz >> 1;   // 0..783 (pairs share bm -> same XCD shares halo source)
    const int bn = swz & 1;
    const int lane = tid & 63;
    const int wv = tid >> 6;
    const int wr = wv >> 1;    // 0..3 (M)
    const int wc = wv & 1;     // 0..1 (N)
    const int l15 = lane & 15;

    const int pfirst = bm * 512;
    const int h0 = pidx(pfirst) - 115;   // >= 0 always (pidx(0) == 115)

    // A ds_read byte bases per m-block: plane(lane>>4) + (pidx(p)-pidx(pfirst))*16
    int al[8];
#pragma unroll
    for (int m = 0; m < 8; ++m) {
        int p = pfirst + wr * 128 + m * 16 + l15;
        al[m] = ((lane >> 4) << 14) + (pidx(p) - h0 - 115) * 16;
    }
    // B per-lane base (shorts): [tap][kc][q=lane>>4][cout][8]
    const unsigned short* bbase = bw + ((lane >> 4) * 256 + bn * 128 + wc * 64 + l15) * 8;

    // halo stage: 4096 slots of 16B, 8 per thread; skip slots past padded image end
#define HSTAGE(KC) do {                                                         \
        _Pragma("unroll")                                                       \
        for (int j = 0; j < 8; ++j) {                                           \
            int s = j * 512 + tid;                                              \
            int kq = s >> 10, q = s & 1023;                                     \
            if (h0 + q < NPADPIX)                                               \
                gl2lds16(xp + (long)(h0 + q) * CIN + (KC) * 32 + kq * 8,        \
                         &Ah[(kq * 1024 + q) * 8]);                             \
        }                                                                       \
    } while (0)

    f32x4 acc[8][4];
#pragma unroll
    for (int m = 0; m < 8; ++m)
#pragma unroll
        for (int n = 0; n < 4; ++n)
            acc[m][n] = (f32x4){0.f, 0.f, 0.f, 0.f};

    short8 breg[2][4];
#pragma unroll
    for (int n = 0; n < 4; ++n)      // B for step 0 (tap0,kc0)
        breg[0][n] = *(const short8*)(bbase + n * 128);

    const char* ah = (const char*)&Ah[0];

#pragma unroll
    for (int st = 0; st < 36; ++st) {
        const int kc = st / 9, tap = st % 9;
        if (tap == 0) {
            __syncthreads();       // prior chunk's reads done (drains all counters)
            HSTAGE(kc);
            __syncthreads();       // halo visible
        }
        if (st < 35) {             // prefetch B for step st+1
            const int st2 = st + 1, kc2 = st2 / 9, tap2 = st2 % 9;
#pragma unroll
            for (int n = 0; n < 4; ++n)
                breg[st2 & 1][n] = *(const short8*)(bbase + (tap2 * 4 + kc2) * 8192 + n * 128);
        }
        const int dh = tap / 3 - 1, dw = tap % 3 - 1;
        const int tshb = (dh * WP + dw + 115) * 16;   // compile-time halo byte shift
#pragma unroll
        for (int mh = 0; mh < 2; ++mh) {
            short8 afr[4];
#pragma unroll
            for (int mi = 0; mi < 4; ++mi)
                afr[mi] = *(const short8*)(ah + al[mh * 4 + mi] + tshb);
#pragma unroll
            for (int mi = 0; mi < 4; ++mi)
#pragma unroll
                for (int n = 0; n < 4; ++n)
                    acc[mh * 4 + mi][n] = __builtin_amdgcn_mfma_f32_16x16x32_bf16(
                        afr[mi], breg[st & 1][n], acc[mh * 4 + mi][n], 0, 0, 0);
        }
    }
#undef HSTAGE

    // ---- epilogue: C/D layout col=lane&15, row=(lane>>4)*4+j ----
    const long row0 = (long)pfirst + wr * 128 + (lane >> 4) * 4;
    const int col = bn * 128 + wc * 64 + l15;
#pragma unroll
    for (int m = 0; m < 8; ++m)
#pragma unroll
        for (int n = 0; n < 4; ++n)
#pragma unroll
            for (int j = 0; j < 4; ++j)
                out[(row0 + m * 16 + j) * COUT + col + n * 16] = acc[m][n][j];
}

// ---------------- fallback (round-1) path: needs no big workspace ----------------
__global__ void binw_kernel(const float* __restrict__ kw, unsigned short* __restrict__ bw) {
    int tid = blockIdx.x * 256 + threadIdx.x;
    int cin5 = tid & 31;
    int cout = (tid >> 5) & 255;
    int kc4  = (tid >> 13) & 3;
    int tap  = tid >> 15;
    int cin  = kc4 * 32 + cin5;
    float w = kw[(tap * 128 + cin) * 256 + cout];
    bw[tid] = (w >= 0.0f) ? (unsigned short)0x3F80u : (unsigned short)0xBF80u;
}

__global__ __launch_bounds__(256, 2)
void conv_fallback_kernel(const float* __restrict__ x, const unsigned short* __restrict__ bw,
                          float* __restrict__ out) {
    __shared__ unsigned short As[128][40];
    __shared__ unsigned short Bs[128][40];
    const int tid = threadIdx.x;
    const int bm = blockIdx.x, bn = blockIdx.y;
    const int lane = tid & 63;
    const int wv = tid >> 6;
    const int wr = wv >> 1, wc = wv & 1;
    const int c4 = (tid & 7) * 4;
    const int rseg = tid >> 3;
    int ohs[4], ows[4], bases[4];
#pragma unroll
    for (int i = 0; i < 4; ++i) {
        int p = bm * 128 + rseg + i * 32;
        int n = p / NPIX;
        int rem = p - n * NPIX;
        int oh = rem / W, ow = rem - oh * W;
        ohs[i] = oh; ows[i] = ow;
        bases[i] = ((n * H + oh) * W + ow) * CIN;
    }
    f32x4 acc[4][4];
#pragma unroll
    for (int m = 0; m < 4; ++m)
#pragma unroll
        for (int n = 0; n < 4; ++n)
            acc[m][n] = (f32x4){0.f, 0.f, 0.f, 0.f};
    const int arow = wr * 64 + (lane & 15);
    const int brow = wc * 64 + (lane & 15);
    const int koff = (lane >> 4) * 8;
    for (int tap = 0; tap < 9; ++tap) {
        const int dh = tap / 3 - 1, dw = tap % 3 - 1;
        const int shift = (dh * W + dw) * CIN;
#pragma unroll
        for (int kc = 0; kc < 4; ++kc) {
            __syncthreads();
#pragma unroll
            for (int i = 0; i < 4; ++i) {
                int ih = ohs[i] + dh, iw = ows[i] + dw;
                bool valid = ((unsigned)ih < (unsigned)H) & ((unsigned)iw < (unsigned)W);
                f32x4 v = {0.f, 0.f, 0.f, 0.f};
                if (valid) v = *(const f32x4*)(x + bases[i] + shift + kc * 32 + c4);
                u16x4 s = { f2bf(v.x), f2bf(v.y), f2bf(v.z), f2bf(v.w) };
                *(u16x4*)&As[rseg + i * 32][c4] = s;
            }
            const unsigned short* bp = bw + tap * 32768 + kc * 8192 + bn * 4096;
#pragma unroll
            for (int j = 0; j < 2; ++j) {
                int idx = tid + j * 256;
                *(u16x8*)&Bs[idx >> 2][(idx & 3) * 8] = *(const u16x8*)(bp + (idx >> 2) * 32 + (idx & 3) * 8);
            }
            __syncthreads();
            short8 af[4], bfr[4];
#pragma unroll
            for (int m = 0; m < 4; ++m)
                af[m] = *(const short8*)&As[arow + m * 16][koff];
#pragma unroll
            for (int n = 0; n < 4; ++n)
                bfr[n] = *(const short8*)&Bs[brow + n * 16][koff];
#pragma unroll
            for (int m = 0; m < 4; ++m)
#pragma unroll
                for (int n = 0; n < 4; ++n)
                    acc[m][n] = __builtin_amdgcn_mfma_f32_16x16x32_bf16(af[m], bfr[n], acc[m][n], 0, 0, 0);
        }
    }
    const long row0 = (long)bm * 128 + wr * 64 + ((lane >> 4) * 4);
    const int col = bn * 128 + wc * 64 + (lane & 15);
#pragma unroll
    for (int m = 0; m < 4; ++m)
#pragma unroll
        for (int n = 0; n < 4; ++n)
#pragma unroll
            for (int j = 0; j < 4; ++j)
                out[(row0 + m * 16 + j) * COUT + col + n * 16] = acc[m][n][j];
}

extern "C" void kernel_launch(void* const* d_in, const int* in_sizes, int n_in,
                              void* d_out, int out_size, void* d_ws, size_t ws_size,
                              hipStream_t stream) {
    const float* x  = (const float*)d_in[0];
    const float* kw = (const float*)d_in[1];
    float* out = (float*)d_out;
    unsigned short* bw = (unsigned short*)d_ws;
    const size_t BW_BYTES = 9 * 4 * 4 * 256 * 8 * 2;      // 589,824
    const size_t PAD_BYTES = (size_t)PADELEMS * 2;        // ~106.5 MB

    if (ws_size >= BW_BYTES + PAD_BYTES) {
        binw3_kernel<<<(9 * 4 * 4 * 256 * 8) / 256, 256, 0, stream>>>(kw, bw);
        unsigned short* xp = (unsigned short*)((char*)d_ws + BW_BYTES);
        pad_kernel<<<(int)((PADELEMS / 8 + 255) / 256), 256, 0, stream>>>(x, xp);
        conv9_kernel<<<(MTOT / 512) * 2, 512, 0, stream>>>(xp, bw, out);
    } else {
        binw_kernel<<<(9 * 256 * 128) / 256, 256, 0, stream>>>(kw, bw);
        dim3 grid(MTOT / 128, COUT / 128);
        conv_fallback_kernel<<<grid, 256, 0, stream>>>(x, bw, out);
    }
}

// Round 10
// 393.752 us; speedup vs baseline: 1.1052x; 1.1052x over previous
//
#include <hip/hip_runtime.h>

typedef __attribute__((ext_vector_type(8))) short short8;
typedef __attribute__((ext_vector_type(4))) float f32x4;
typedef __attribute__((ext_vector_type(4))) unsigned short u16x4;
typedef __attribute__((ext_vector_type(8))) unsigned short u16x8;

#define H 112
#define W 112
#define HP 114
#define WP 114
#define CIN 128
#define COUT 256
#define NPIX (H * W)          // 12544
#define NIMG 32
#define MTOT (NIMG * NPIX)    // 401408
#define PADELEMS ((long)NIMG * HP * WP * CIN)  // 53,231,616
#define NPADPIX (NIMG * HP * WP)               // 415,872 padded pixels

__device__ __forceinline__ unsigned short f2bf(float f) {
    unsigned int u = __builtin_bit_cast(unsigned int, f);
    u += 0x7FFFu + ((u >> 16) & 1u);
    return (unsigned short)(u >> 16);
}

__device__ __forceinline__ void gl2lds16(const void* g, void* l) {
    __builtin_amdgcn_global_load_lds(
        (const __attribute__((address_space(1))) unsigned int*)g,
        (__attribute__((address_space(3))) unsigned int*)l,
        16, 0, 0);
}

// output pixel p -> padded-image linear pixel index
__device__ __forceinline__ int pidx(int p) {
    int n = p / NPIX;
    int r = p - n * NPIX;
    int oh = r / W, ow = r - oh * W;
    return n * (HP * WP) + (oh + 1) * WP + ow + 1;
}

// ---- weights bf16 {+1,-1}, layout [tap][kc4][kq4][cout256][e8] ----
__global__ void binw3_kernel(const float* __restrict__ kw, unsigned short* __restrict__ bw) {
    int tid = blockIdx.x * 256 + threadIdx.x;
    int e    = tid & 7;
    int cout = (tid >> 3) & 255;
    int q    = (tid >> 11) & 3;
    int kc   = (tid >> 13) & 3;
    int tap  = tid >> 15;
    int cin  = kc * 32 + q * 8 + e;
    float w = kw[(tap * 128 + cin) * 256 + cout];
    bw[tid] = (w >= 0.0f) ? (unsigned short)0x3F80u : (unsigned short)0xBF80u;
}

// ---- x (f32 NHWC) -> zero-padded bf16 [N][114][114][128] ----
__global__ void pad_kernel(const float* __restrict__ x, unsigned short* __restrict__ xp) {
    long tid = (long)blockIdx.x * 256 + threadIdx.x;   // one thread = 8 elems
    if (tid >= PADELEMS / 8) return;
    int c8 = (int)(tid & 15);
    long rem = tid >> 4;
    int wp = (int)(rem % WP); rem /= WP;
    int hp = (int)(rem % HP);
    int n  = (int)(rem / HP);
    u16x8 v = {0, 0, 0, 0, 0, 0, 0, 0};
    if (hp >= 1 && hp <= H && wp >= 1 && wp <= W) {
        const float* s = x + (((long)(n * H + hp - 1) * W + (wp - 1)) * CIN + c8 * 8);
        f32x4 a = *(const f32x4*)s;
        f32x4 b = *(const f32x4*)(s + 4);
        v = (u16x8){ f2bf(a.x), f2bf(a.y), f2bf(a.z), f2bf(a.w),
                     f2bf(b.x), f2bf(b.y), f2bf(b.z), f2bf(b.w) };
    }
    *(u16x8*)(xp + tid * 8) = v;
}

// ---- conv10: A-halo LDS + B LDS, both staged once per cin-chunk ----
// BM=512 x BN=128, 8 waves (4M x 2N), per-wave 128x64. Barrier-free 9-tap
// inner loop (read-only LDS); 2 barriers per cin-chunk = 8 total.
__global__ __launch_bounds__(512, 2)
void conv10_kernel(const unsigned short* __restrict__ xp, const unsigned short* __restrict__ bw,
                   float* __restrict__ out) {
    __shared__ unsigned short Ah[4 * 1024 * 8];     // 64 KB halo [kq][slot1024][8]
    __shared__ unsigned short Bl[9 * 4 * 128 * 8];  // 72 KB     [tap][kq][col128][8]

    const int tid = threadIdx.x;
    const int swz = (blockIdx.x & 7) * 196 + (blockIdx.x >> 3);  // 1568 = 8*196
    const int bm = swz >> 1;   // pairs share bm (same XCD reuses halo source)
    const int bn = swz & 1;
    const int lane = tid & 63;
    const int wv = tid >> 6;
    const int wr = wv >> 1;    // 0..3 (M)
    const int wc = wv & 1;     // 0..1 (N)
    const int l15 = lane & 15;
    const int kq = lane >> 4;

    const int pfirst = bm * 512;
    const int h0 = pidx(pfirst) - 115;   // >= 0 (pidx(0) == 115)

    // A ds_read byte bases per m-block (proven in conv9)
    int al[8];
#pragma unroll
    for (int m = 0; m < 8; ++m) {
        int p = pfirst + wr * 128 + m * 16 + l15;
        al[m] = (kq << 14) + (pidx(p) - h0 - 115) * 16;
    }
    // B ds_read byte base: + tap*8192 + n*256
    const int bbyte = (kq * 128 + wc * 64 + l15) * 16;

    f32x4 acc[8][4];
#pragma unroll
    for (int m = 0; m < 8; ++m)
#pragma unroll
        for (int n = 0; n < 4; ++n)
            acc[m][n] = (f32x4){0.f, 0.f, 0.f, 0.f};

    const char* ah = (const char*)&Ah[0];
    const char* bb = (const char*)&Bl[0];

    for (int kc = 0; kc < 4; ++kc) {
        __syncthreads();   // prior chunk's LDS reads complete
        // stage halo: 4096 slots x 16B (8/thread), linear dest
#pragma unroll
        for (int j = 0; j < 8; ++j) {
            int s = j * 512 + tid;
            int q = s & 1023;
            if (h0 + q < NPADPIX)
                gl2lds16(xp + (long)(h0 + q) * CIN + kc * 32 + (s >> 10) * 8,
                         &Ah[s * 8]);
        }
        // stage B: 4608 slots x 16B (9/thread), linear dest
#pragma unroll
        for (int j = 0; j < 9; ++j) {
            int s = j * 512 + tid;
            int tap = s >> 9, r = s & 511;          // r = q*128 + col
            gl2lds16(bw + (((tap * 4 + kc) * 4) * 256 + bn * 128 + r) * 8
                        + (r >> 7) * (256 - 128) * 8,   // q*256*8 adjust: (q*256+col) vs r
                     &Bl[s * 8]);
        }
        __syncthreads();   // staged data visible (full vmcnt drain)

#pragma unroll
        for (int tap = 0; tap < 9; ++tap) {
            const int dh = tap / 3 - 1, dw = tap % 3 - 1;
            const int tshb = (dh * WP + dw + 115) * 16;   // compile-time halo shift
            short8 bfr[4];
#pragma unroll
            for (int n = 0; n < 4; ++n)
                bfr[n] = *(const short8*)(bb + tap * 8192 + bbyte + n * 256);
#pragma unroll
            for (int mh = 0; mh < 2; ++mh) {
                short8 afr[4];
#pragma unroll
                for (int mi = 0; mi < 4; ++mi)
                    afr[mi] = *(const short8*)(ah + al[mh * 4 + mi] + tshb);
#pragma unroll
                for (int mi = 0; mi < 4; ++mi)
#pragma unroll
                    for (int n = 0; n < 4; ++n)
                        acc[mh * 4 + mi][n] = __builtin_amdgcn_mfma_f32_16x16x32_bf16(
                            afr[mi], bfr[n], acc[mh * 4 + mi][n], 0, 0, 0);
            }
        }
    }

    // ---- epilogue: C/D layout col=lane&15, row=(lane>>4)*4+j (proven) ----
    const long row0 = (long)pfirst + wr * 128 + kq * 4;
    const int col = bn * 128 + wc * 64 + l15;
#pragma unroll
    for (int m = 0; m < 8; ++m)
#pragma unroll
        for (int n = 0; n < 4; ++n)
#pragma unroll
            for (int j = 0; j < 4; ++j)
                out[(row0 + m * 16 + j) * COUT + col + n * 16] = acc[m][n][j];
}

// ---------------- fallback (round-1) path: needs no big workspace ----------------
__global__ void binw_kernel(const float* __restrict__ kw, unsigned short* __restrict__ bw) {
    int tid = blockIdx.x * 256 + threadIdx.x;
    int cin5 = tid & 31;
    int cout = (tid >> 5) & 255;
    int kc4  = (tid >> 13) & 3;
    int tap  = tid >> 15;
    int cin  = kc4 * 32 + cin5;
    float w = kw[(tap * 128 + cin) * 256 + cout];
    bw[tid] = (w >= 0.0f) ? (unsigned short)0x3F80u : (unsigned short)0xBF80u;
}

__global__ __launch_bounds__(256, 2)
void conv_fallback_kernel(const float* __restrict__ x, const unsigned short* __restrict__ bw,
                          float* __restrict__ out) {
    __shared__ unsigned short As[128][40];
    __shared__ unsigned short Bs[128][40];
    const int tid = threadIdx.x;
    const int bm = blockIdx.x, bn = blockIdx.y;
    const int lane = tid & 63;
    const int wv = tid >> 6;
    const int wr = wv >> 1, wc = wv & 1;
    const int c4 = (tid & 7) * 4;
    const int rseg = tid >> 3;
    int ohs[4], ows[4], bases[4];
#pragma unroll
    for (int i = 0; i < 4; ++i) {
        int p = bm * 128 + rseg + i * 32;
        int n = p / NPIX;
        int rem = p - n * NPIX;
        int oh = rem / W, ow = rem - oh * W;
        ohs[i] = oh; ows[i] = ow;
        bases[i] = ((n * H + oh) * W + ow) * CIN;
    }
    f32x4 acc[4][4];
#pragma unroll
    for (int m = 0; m < 4; ++m)
#pragma unroll
        for (int n = 0; n < 4; ++n)
            acc[m][n] = (f32x4){0.f, 0.f, 0.f, 0.f};
    const int arow = wr * 64 + (lane & 15);
    const int brow = wc * 64 + (lane & 15);
    const int koff = (lane >> 4) * 8;
    for (int tap = 0; tap < 9; ++tap) {
        const int dh = tap / 3 - 1, dw = tap % 3 - 1;
        const int shift = (dh * W + dw) * CIN;
#pragma unroll
        for (int kc = 0; kc < 4; ++kc) {
            __syncthreads();
#pragma unroll
            for (int i = 0; i < 4; ++i) {
                int ih = ohs[i] + dh, iw = ows[i] + dw;
                bool valid = ((unsigned)ih < (unsigned)H) & ((unsigned)iw < (unsigned)W);
                f32x4 v = {0.f, 0.f, 0.f, 0.f};
                if (valid) v = *(const f32x4*)(x + bases[i] + shift + kc * 32 + c4);
                u16x4 s = { f2bf(v.x), f2bf(v.y), f2bf(v.z), f2bf(v.w) };
                *(u16x4*)&As[rseg + i * 32][c4] = s;
            }
            const unsigned short* bp = bw + tap * 32768 + kc * 8192 + bn * 4096;
#pragma unroll
            for (int j = 0; j < 2; ++j) {
                int idx = tid + j * 256;
                *(u16x8*)&Bs[idx >> 2][(idx & 3) * 8] = *(const u16x8*)(bp + (idx >> 2) * 32 + (idx & 3) * 8);
            }
            __syncthreads();
            short8 af[4], bfr[4];
#pragma unroll
            for (int m = 0; m < 4; ++m)
                af[m] = *(const short8*)&As[arow + m * 16][koff];
#pragma unroll
            for (int n = 0; n < 4; ++n)
                bfr[n] = *(const short8*)&Bs[brow + n * 16][koff];
#pragma unroll
            for (int m = 0; m < 4; ++m)
#pragma unroll
                for (int n = 0; n < 4; ++n)
                    acc[m][n] = __builtin_amdgcn_mfma_f32_16x16x32_bf16(af[m], bfr[n], acc[m][n], 0, 0, 0);
        }
    }
    const long row0 = (long)bm * 128 + wr * 64 + ((lane >> 4) * 4);
    const int col = bn * 128 + wc * 64 + (lane & 15);
#pragma unroll
    for (int m = 0; m < 4; ++m)
#pragma unroll
        for (int n = 0; n < 4; ++n)
#pragma unroll
            for (int j = 0; j < 4; ++j)
                out[(row0 + m * 16 + j) * COUT + col + n * 16] = acc[m][n][j];
}

extern "C" void kernel_launch(void* const* d_in, const int* in_sizes, int n_in,
                              void* d_out, int out_size, void* d_ws, size_t ws_size,
                              hipStream_t stream) {
    const float* x  = (const float*)d_in[0];
    const float* kw = (const float*)d_in[1];
    float* out = (float*)d_out;
    unsigned short* bw = (unsigned short*)d_ws;
    const size_t BW_BYTES = 9 * 4 * 4 * 256 * 8 * 2;      // 589,824
    const size_t PAD_BYTES = (size_t)PADELEMS * 2;        // ~106.5 MB

    if (ws_size >= BW_BYTES + PAD_BYTES) {
        binw3_kernel<<<(9 * 4 * 4 * 256 * 8) / 256, 256, 0, stream>>>(kw, bw);
        unsigned short* xp = (unsigned short*)((char*)d_ws + BW_BYTES);
        pad_kernel<<<(int)((PADELEMS / 8 + 255) / 256), 256, 0, stream>>>(x, xp);
        conv10_kernel<<<(MTOT / 512) * 2, 512, 0, stream>>>(xp, bw, out);
    } else {
        binw_kernel<<<(9 * 256 * 128) / 256, 256, 0, stream>>>(kw, bw);
        dim3 grid(MTOT / 128, COUT / 128);
        conv_fallback_kernel<<<grid, 256, 0, stream>>>(x, bw, out);
    }
}